// Round 7
// baseline (369.884 us; speedup 1.0000x reference)
//
#include <hip/hip_runtime.h>
#include <hip/hip_bf16.h>

// CausalSelfAttention: B=4, S=2048, D=1024, H=16, Dh=64. fp32 in/out, bf16 MFMA compute.
//
// Pipeline (all on `stream`):
//   1. convert_x: x fp32 -> bf16 (8192x1024)
//   2. transpose_w: Wq|Wk|Wv -> wqkvt (3072x1024 bf16, N-major), Wo -> wot
//   3. pack_bqkv: [bq|bk|bv] -> fp32 (3072)
//   4. gemm<0>: qkv = xb @ [Wq|Wk|Wv] + b  -> qk bf16 (8192x2048, Q pre-scaled by
//               0.125*log2e) + vt (B,H,Dh,S) scatter
//   5. attn: flash attention, 2 waves/block, 64 q/block, grid 2048 blocks (5/CU resident)
//   6. gemm<1>: out = attn @ Wo + bo       -> fp32 d_out

typedef __bf16 bf16x8 __attribute__((ext_vector_type(8)));
typedef float f32x4 __attribute__((ext_vector_type(4)));
typedef unsigned short u16;

__device__ __forceinline__ u16 f2b(float f) {
    __hip_bfloat16 h = __float2bfloat16(f);
    return __builtin_bit_cast(unsigned short, h);
}

__device__ __forceinline__ f32x4 mfma16(bf16x8 a, bf16x8 b, f32x4 c) {
    return __builtin_amdgcn_mfma_f32_16x16x32_bf16(a, b, c, 0, 0, 0);
}

typedef const __attribute__((address_space(1))) unsigned int* gas1_t;
typedef __attribute__((address_space(3))) unsigned int* las3_t;
__device__ __forceinline__ void gld16(const void* g, void* l) {
    __builtin_amdgcn_global_load_lds((gas1_t)g, (las3_t)l, 16, 0, 0);
}

// ---------------------------------------------------------------- conversions
__global__ __launch_bounds__(256) void convert_x(const float* __restrict__ x,
                                                 u16* __restrict__ xb, int n4) {
    int i = blockIdx.x * 256 + threadIdx.x;
    if (i < n4) {
        float4 v = ((const float4*)x)[i];
        ushort4 u;
        u.x = f2b(v.x); u.y = f2b(v.y); u.z = f2b(v.z); u.w = f2b(v.w);
        ((ushort4*)xb)[i] = u;
    }
}

// W (K=1024 rows, N=1024 cols) fp32 -> Wt (N,K) bf16. z selects matrix.
__global__ __launch_bounds__(256) void transpose_w(const float* __restrict__ Wq,
                                                   const float* __restrict__ Wk,
                                                   const float* __restrict__ Wv,
                                                   const float* __restrict__ Wo,
                                                   u16* __restrict__ wqkvt,
                                                   u16* __restrict__ wot) {
    const int z = blockIdx.z;
    const float* src = (z == 0) ? Wq : (z == 1) ? Wk : (z == 2) ? Wv : Wo;
    u16* dst = (z == 3) ? wot : (wqkvt + (size_t)z * 1024 * 1024);
    __shared__ float tile[32][33];
    const int tx = threadIdx.x, ty = threadIdx.y;  // block (32,8)
    const int nbase = blockIdx.x * 32, kbase = blockIdx.y * 32;
    for (int j = 0; j < 4; ++j)
        tile[ty + j * 8][tx] = src[(size_t)(kbase + ty + j * 8) * 1024 + nbase + tx];
    __syncthreads();
    for (int j = 0; j < 4; ++j)
        dst[(size_t)(nbase + ty + j * 8) * 1024 + kbase + tx] = f2b(tile[tx][ty + j * 8]);
}

__global__ __launch_bounds__(256) void pack_bqkv(const float* __restrict__ bq,
                                                 const float* __restrict__ bk,
                                                 const float* __restrict__ bv,
                                                 float* __restrict__ bqkv) {
    int i = blockIdx.x * 256 + threadIdx.x;  // 3072 total
    bqkv[i] = (i < 1024) ? bq[i] : (i < 2048) ? bk[i - 1024] : bv[i - 2048];
}

// ---------------------------------------------------------------- GEMM (m97-style)
// C(M,N) = A(M,K) @ Bt(N,K)^T + bias. 128x128 tile, BK=32, 256 thr = 4 waves.
// MODE 0: QKV-combined: cols <1024 -> Q (pre-scaled by 0.125*log2e) into qk;
//         1024..2047 -> K into qk; >=2048 -> V^T scatter into Cout2.
// MODE 1: fp32 row-major out.
template <int MODE>
__global__ __launch_bounds__(256) void gemm_bt(const u16* __restrict__ A,
                                               const u16* __restrict__ Bt,
                                               const float* __restrict__ bias,
                                               void* __restrict__ Cout,
                                               void* __restrict__ Cout2,
                                               int M, int N, int K, int ldc) {
    const int tid = threadIdx.x;
    const int l = tid & 63;
    const int w = tid >> 6;
    const int tileM = blockIdx.x * 128;
    const int tileN = blockIdx.y * 128;

    __shared__ u16 As[128 * 32];
    __shared__ u16 Bs[128 * 32];

    const int srow = l >> 2;
    const int schunk = l & 3;
    const int mrow = l & 15;
    const int g8 = (l >> 4) * 8;
    const int waveM = (w & 1) * 64;
    const int waveN = (w >> 1) * 64;

    f32x4 acc[4][4] = {};

    for (int k0 = 0; k0 < K; k0 += 32) {
        gld16(A + (size_t)(tileM + w * 32 + srow) * K + k0 + schunk * 8, &As[(w * 2) * 512]);
        gld16(A + (size_t)(tileM + w * 32 + 16 + srow) * K + k0 + schunk * 8, &As[(w * 2 + 1) * 512]);
        gld16(Bt + (size_t)(tileN + w * 32 + srow) * K + k0 + schunk * 8, &Bs[(w * 2) * 512]);
        gld16(Bt + (size_t)(tileN + w * 32 + 16 + srow) * K + k0 + schunk * 8, &Bs[(w * 2 + 1) * 512]);
        __syncthreads();

        bf16x8 af[4], bf[4];
        for (int im = 0; im < 4; ++im)
            af[im] = *(const bf16x8*)&As[(waveM + im * 16 + mrow) * 32 + g8];
        for (int in = 0; in < 4; ++in)
            bf[in] = *(const bf16x8*)&Bs[(waveN + in * 16 + mrow) * 32 + g8];
        for (int im = 0; im < 4; ++im)
            for (int in = 0; in < 4; ++in)
                acc[im][in] = mfma16(af[im], bf[in], acc[im][in]);
        __syncthreads();
    }

    // epilogue. C/D layout: row=(l>>4)*4+r, col=l&15  [m89/m91]
    const int rbase = (l >> 4) * 4;
    for (int im = 0; im < 4; ++im) {
        for (int in = 0; in < 4; ++in) {
            const int gm0 = tileM + waveM + im * 16 + rbase;
            const int gn = tileN + waveN + in * 16 + (l & 15);
            const float bv_ = bias[gn];
            if (MODE == 1) {
                float* out = (float*)Cout;
                for (int r = 0; r < 4; ++r)
                    out[(size_t)(gm0 + r) * ldc + gn] = acc[im][in][r] + bv_;
            } else if (tileN < 2048) {
                // fold softmax scale * log2e into Q so attn softmax needs no scaling
                const float qs = (tileN < 1024) ? 0.125f * 1.4426950408889634f : 1.0f;
                u16* out = (u16*)Cout;  // qk, row-major (token, 2048)
                for (int r = 0; r < 4; ++r)
                    out[(size_t)(gm0 + r) * 2048 + gn] = f2b((acc[im][in][r] + bv_) * qs);
            } else {
                u16* out = (u16*)Cout2;  // V^T scatter (B,H,Dh,S)
                const int b = gm0 >> 11, s0 = gm0 & 2047;
                const int gn2 = gn - 2048;
                const int h = gn2 >> 6, dh = gn2 & 63;
                ushort4 u;
                u.x = f2b(acc[im][in][0] + bv_);
                u.y = f2b(acc[im][in][1] + bv_);
                u.z = f2b(acc[im][in][2] + bv_);
                u.w = f2b(acc[im][in][3] + bv_);
                *(ushort4*)&out[((size_t)((b * 16 + h) * 64 + dh)) * 2048 + s0] = u;
            }
        }
    }
}

// ---------------------------------------------------------------- flash attention
// 128 thr = 2 waves/block, 64 queries/block (wave w owns [q0+w*32, +32) as two
// 16-col groups). Coalesced register-staged K/V -> LDS (R4-proven), one q-tile
// per block. Grid (bh=64, qtile=32) = 2048 blocks -> 5 blocks/CU resident
// (LDS 27 KB), big tiles first (qt = 31-y), bh%8 XCD striping preserved.
// Q arrives pre-scaled by 0.125*log2e (folded into gemm<0>).
__global__ __launch_bounds__(128) void attn_kernel(const u16* __restrict__ qk,
                                                   const u16* __restrict__ vt,
                                                   u16* __restrict__ attn) {
    const int bh = blockIdx.x;
    const int qt = 31 - (int)blockIdx.y;  // big q-tiles launch first
    const int b = bh >> 4, h = bh & 15;
    const int q0 = qt * 64;
    const int tid = threadIdx.x, l = tid & 63, w = tid >> 6;
    const int q = l & 15;   // query column within group
    const int g = l >> 4;   // k-group
    const int g8 = g * 8;

    __shared__ u16 Ks[64 * 72];  // [key][dh]
    __shared__ u16 Vs[64 * 72];  // [dh][key]
    __shared__ u16 Ps[64 * 72];  // Q staging, then per-wave P slabs [query][key]

    const int srow = tid >> 3, sch = tid & 7;  // staging: 16 rows x 8 chunks, x4 passes
    const u16* kgb = qk + (size_t)(b * 2048 + srow) * 2048 + 1024 + h * 64 + sch * 8;
    const u16* vgb = vt + (size_t)(bh * 64 + srow) * 2048 + sch * 8;

    // stage Q tile (64 rows x 64 cols): 4 passes of 128 thr x 16B
    for (int i = 0; i < 4; ++i) {
        const int idx = i * 128 + tid;
        const int row = idx >> 3, ch = idx & 7;
        *(uint4*)&Ps[row * 72 + ch * 8] =
            *(const uint4*)&qk[(size_t)(b * 2048 + q0 + row) * 2048 + h * 64 + ch * 8];
    }
    __syncthreads();
    bf16x8 qb[2][2];  // [col-group][kh]
    for (int c = 0; c < 2; ++c) {
        qb[c][0] = *(const bf16x8*)&Ps[(w * 32 + c * 16 + q) * 72 + g8];
        qb[c][1] = *(const bf16x8*)&Ps[(w * 32 + c * 16 + q) * 72 + 32 + g8];
    }

    float m2[2] = {-1e30f, -1e30f}, li[2] = {0.f, 0.f};
    f32x4 o[2][4] = {};
    const int tmax = qt;  // tiles 0..qt cover keys 0..q0+63

    uint4 kreg[4], vreg[4];  // coalesced prefetch of tile 0 (16 rows/pass x 4)
    for (int j = 0; j < 4; ++j) {
        kreg[j] = *(const uint4*)(kgb + (size_t)(j * 16) * 2048);
        vreg[j] = *(const uint4*)(vgb + (size_t)(j * 16) * 2048);
    }

    for (int t = 0; t <= tmax; ++t) {
        __syncthreads();  // prev tile compute done
        for (int j = 0; j < 4; ++j) {
            *(uint4*)&Ks[(srow + j * 16) * 72 + sch * 8] = kreg[j];
            *(uint4*)&Vs[(srow + j * 16) * 72 + sch * 8] = vreg[j];
        }
        __syncthreads();  // staging visible
        if (t < tmax) {   // coalesced prefetch of tile t+1 (overlaps compute)
            for (int j = 0; j < 4; ++j) {
                // K rows are tokens: advance (t+1)*64 rows
                kreg[j] = *(const uint4*)(kgb + (size_t)((t + 1) * 64 + j * 16) * 2048);
                // V^T rows are dh: key tile advances along COLUMNS (+64 elems/tile)
                vreg[j] = *(const uint4*)(vgb + (size_t)(j * 16) * 2048 + (t + 1) * 64);
            }
        }
        const int kv0 = t * 64;

        // S^T = K @ Q^T : K A-frags shared across both query groups
        f32x4 st[2][4] = {};
        for (int kh = 0; kh < 2; ++kh)
            for (int cb = 0; cb < 4; ++cb) {
                bf16x8 ka = *(const bf16x8*)&Ks[(cb * 16 + q) * 72 + kh * 32 + g8];
                st[0][cb] = mfma16(ka, qb[0][kh], st[0][cb]);
                st[1][cb] = mfma16(ka, qb[1][kh], st[1][cb]);
            }
        for (int c = 0; c < 2; ++c) {
            if (t == tmax) {  // only the diagonal tile has masked keys
                const int qg = q0 + w * 32 + c * 16 + q;
                for (int cb = 0; cb < 4; ++cb)
                    for (int r = 0; r < 4; ++r) {
                        const int key = kv0 + cb * 16 + g * 4 + r;
                        if (key > qg) st[c][cb][r] = -1e30f;
                    }
            }
            float mx = st[c][0][0];
            for (int cb = 0; cb < 4; ++cb)
                for (int r = 0; r < 4; ++r) mx = fmaxf(mx, st[c][cb][r]);
            mx = fmaxf(mx, __shfl_xor(mx, 16));
            mx = fmaxf(mx, __shfl_xor(mx, 32));
            const float mnew = fmaxf(m2[c], mx);
            const float alpha = __builtin_amdgcn_exp2f(m2[c] - mnew);
            m2[c] = mnew;
            float ps = 0.f;
            for (int cb = 0; cb < 4; ++cb)
                for (int r = 0; r < 4; ++r) {
                    const float p = __builtin_amdgcn_exp2f(st[c][cb][r] - mnew);
                    st[c][cb][r] = p;
                    ps += p;
                }
            ps += __shfl_xor(ps, 16);
            ps += __shfl_xor(ps, 32);
            li[c] = li[c] * alpha + ps;
            for (int cb = 0; cb < 4; ++cb) o[c][cb] *= alpha;
            // P^T C-regs -> Ps[query][key] (r=0..3 consecutive keys -> b64)
            for (int cb = 0; cb < 4; ++cb) {
                ushort4 u;
                u.x = f2b(st[c][cb][0]); u.y = f2b(st[c][cb][1]);
                u.z = f2b(st[c][cb][2]); u.w = f2b(st[c][cb][3]);
                *(ushort4*)&Ps[(w * 32 + c * 16 + q) * 72 + cb * 16 + g * 4] = u;
            }
        }
        __builtin_amdgcn_s_waitcnt(0xC07F);  // lgkmcnt(0); DS in-order per wave
        // O^T += V^T @ P^T : V A-frags shared across both query groups
        for (int kh = 0; kh < 2; ++kh) {
            bf16x8 pb0 = *(const bf16x8*)&Ps[(w * 32 + q) * 72 + kh * 32 + g8];
            bf16x8 pb1 = *(const bf16x8*)&Ps[(w * 32 + 16 + q) * 72 + kh * 32 + g8];
            for (int cb = 0; cb < 4; ++cb) {
                bf16x8 va = *(const bf16x8*)&Vs[(cb * 16 + q) * 72 + kh * 32 + g8];
                o[0][cb] = mfma16(va, pb0, o[0][cb]);
                o[1][cb] = mfma16(va, pb1, o[1][cb]);
            }
        }
    }

    // epilogue: attn[token][h*64+dh], dh = cb*16+g*4+r contiguous
    for (int c = 0; c < 2; ++c) {
        const float inv = 1.0f / li[c];
        const size_t tok = (size_t)(b * 2048 + q0 + w * 32 + c * 16 + q);
        for (int cb = 0; cb < 4; ++cb) {
            ushort4 u;
            u.x = f2b(o[c][cb][0] * inv); u.y = f2b(o[c][cb][1] * inv);
            u.z = f2b(o[c][cb][2] * inv); u.w = f2b(o[c][cb][3] * inv);
            *(ushort4*)&attn[tok * 1024 + h * 64 + cb * 16 + g * 4] = u;
        }
    }
}

// ---------------------------------------------------------------- launch
extern "C" void kernel_launch(void* const* d_in, const int* in_sizes, int n_in,
                              void* d_out, int out_size, void* d_ws, size_t ws_size,
                              hipStream_t stream) {
    const float* x  = (const float*)d_in[0];
    const float* Wq = (const float*)d_in[1];
    const float* bq = (const float*)d_in[2];
    const float* Wk = (const float*)d_in[3];
    const float* bk = (const float*)d_in[4];
    const float* Wv = (const float*)d_in[5];
    const float* bv = (const float*)d_in[6];
    const float* Wo = (const float*)d_in[7];
    const float* bo = (const float*)d_in[8];
    float* out = (float*)d_out;

    char* ws = (char*)d_ws;
    size_t off = 0;
    auto alloc = [&](size_t bytes) -> void* {
        void* p = ws + off;
        off += (bytes + 255) & ~(size_t)255;
        return p;
    };
    u16*   xb    = (u16*)alloc(8192ull * 1024 * 2);   // x bf16
    u16*   wqkvt = (u16*)alloc(3072ull * 1024 * 2);   // [Wq|Wk|Wv]^T (N,K)
    u16*   wot   = (u16*)alloc(1024ull * 1024 * 2);   // Wo^T
    float* bqkv  = (float*)alloc(3072ull * 4);
    u16*   qk    = (u16*)alloc(8192ull * 2048 * 2);   // [q|k] (token, 2048)
    u16*   vt    = (u16*)alloc(8192ull * 1024 * 2);   // V^T (B,H,Dh,S)
    u16*   attn  = (u16*)alloc(8192ull * 1024 * 2);   // attention out (token, D)

    convert_x<<<8192, 256, 0, stream>>>(x, xb, 8192 * 1024 / 4);
    transpose_w<<<dim3(32, 32, 4), dim3(32, 8), 0, stream>>>(Wq, Wk, Wv, Wo, wqkvt, wot);
    pack_bqkv<<<12, 256, 0, stream>>>(bq, bk, bv, bqkv);
    gemm_bt<0><<<dim3(64, 24), 256, 0, stream>>>(xb, wqkvt, bqkv, qk, vt, 8192, 3072, 1024, 0);
    attn_kernel<<<dim3(64, 32), 128, 0, stream>>>(qk, vt, attn);
    gemm_bt<1><<<dim3(64, 8), 256, 0, stream>>>(attn, wot, bo, out, nullptr, 8192, 1024, 1024, 1024);
}

// Round 8
// 306.086 us; speedup vs baseline: 1.2084x; 1.2084x over previous
//
#include <hip/hip_runtime.h>
#include <hip/hip_bf16.h>

// CausalSelfAttention: B=4, S=2048, D=1024, H=16, Dh=64. fp32 in/out, bf16 MFMA compute.
//
// Pipeline (all on `stream`):
//   1. convert_x: x fp32 -> bf16 (8192x1024)
//   2. transpose_w: Wq|Wk|Wv -> wqkvt (3072x1024 bf16, N-major), Wo -> wot
//   3. pack_bqkv: [bq|bk|bv] -> fp32 (3072)
//   4. gemm<0>: qkv = xb @ [Wq|Wk|Wv] + b  -> qk bf16 (8192x2048, Q pre-scaled by
//               0.125*log2e) + vt (B,H,Dh,S) scatter
//   5. attn: flash attention, 4 waves/block, 128 q/block, grid 1024 blocks (4/CU resident)
//   6. gemm<1>: out = attn @ Wo + bo       -> fp32 d_out

typedef __bf16 bf16x8 __attribute__((ext_vector_type(8)));
typedef float f32x4 __attribute__((ext_vector_type(4)));
typedef unsigned short u16;

__device__ __forceinline__ u16 f2b(float f) {
    __hip_bfloat16 h = __float2bfloat16(f);
    return __builtin_bit_cast(unsigned short, h);
}

__device__ __forceinline__ f32x4 mfma16(bf16x8 a, bf16x8 b, f32x4 c) {
    return __builtin_amdgcn_mfma_f32_16x16x32_bf16(a, b, c, 0, 0, 0);
}

typedef const __attribute__((address_space(1))) unsigned int* gas1_t;
typedef __attribute__((address_space(3))) unsigned int* las3_t;
__device__ __forceinline__ void gld16(const void* g, void* l) {
    __builtin_amdgcn_global_load_lds((gas1_t)g, (las3_t)l, 16, 0, 0);
}

// ---------------------------------------------------------------- conversions
__global__ __launch_bounds__(256) void convert_x(const float* __restrict__ x,
                                                 u16* __restrict__ xb, int n4) {
    int i = blockIdx.x * 256 + threadIdx.x;
    if (i < n4) {
        float4 v = ((const float4*)x)[i];
        ushort4 u;
        u.x = f2b(v.x); u.y = f2b(v.y); u.z = f2b(v.z); u.w = f2b(v.w);
        ((ushort4*)xb)[i] = u;
    }
}

// W (K=1024 rows, N=1024 cols) fp32 -> Wt (N,K) bf16. z selects matrix.
__global__ __launch_bounds__(256) void transpose_w(const float* __restrict__ Wq,
                                                   const float* __restrict__ Wk,
                                                   const float* __restrict__ Wv,
                                                   const float* __restrict__ Wo,
                                                   u16* __restrict__ wqkvt,
                                                   u16* __restrict__ wot) {
    const int z = blockIdx.z;
    const float* src = (z == 0) ? Wq : (z == 1) ? Wk : (z == 2) ? Wv : Wo;
    u16* dst = (z == 3) ? wot : (wqkvt + (size_t)z * 1024 * 1024);
    __shared__ float tile[32][33];
    const int tx = threadIdx.x, ty = threadIdx.y;  // block (32,8)
    const int nbase = blockIdx.x * 32, kbase = blockIdx.y * 32;
    for (int j = 0; j < 4; ++j)
        tile[ty + j * 8][tx] = src[(size_t)(kbase + ty + j * 8) * 1024 + nbase + tx];
    __syncthreads();
    for (int j = 0; j < 4; ++j)
        dst[(size_t)(nbase + ty + j * 8) * 1024 + kbase + tx] = f2b(tile[tx][ty + j * 8]);
}

__global__ __launch_bounds__(256) void pack_bqkv(const float* __restrict__ bq,
                                                 const float* __restrict__ bk,
                                                 const float* __restrict__ bv,
                                                 float* __restrict__ bqkv) {
    int i = blockIdx.x * 256 + threadIdx.x;  // 3072 total
    bqkv[i] = (i < 1024) ? bq[i] : (i < 2048) ? bk[i - 1024] : bv[i - 2048];
}

// ---------------------------------------------------------------- GEMM (m97-style)
// C(M,N) = A(M,K) @ Bt(N,K)^T + bias. 128x128 tile, BK=32, 256 thr = 4 waves.
// MODE 0: QKV-combined: cols <1024 -> Q (pre-scaled by 0.125*log2e) into qk;
//         1024..2047 -> K into qk; >=2048 -> V^T scatter into Cout2.
// MODE 1: fp32 row-major out.
template <int MODE>
__global__ __launch_bounds__(256) void gemm_bt(const u16* __restrict__ A,
                                               const u16* __restrict__ Bt,
                                               const float* __restrict__ bias,
                                               void* __restrict__ Cout,
                                               void* __restrict__ Cout2,
                                               int M, int N, int K, int ldc) {
    const int tid = threadIdx.x;
    const int l = tid & 63;
    const int w = tid >> 6;
    const int tileM = blockIdx.x * 128;
    const int tileN = blockIdx.y * 128;

    __shared__ u16 As[128 * 32];
    __shared__ u16 Bs[128 * 32];

    const int srow = l >> 2;
    const int schunk = l & 3;
    const int mrow = l & 15;
    const int g8 = (l >> 4) * 8;
    const int waveM = (w & 1) * 64;
    const int waveN = (w >> 1) * 64;

    f32x4 acc[4][4] = {};

    for (int k0 = 0; k0 < K; k0 += 32) {
        gld16(A + (size_t)(tileM + w * 32 + srow) * K + k0 + schunk * 8, &As[(w * 2) * 512]);
        gld16(A + (size_t)(tileM + w * 32 + 16 + srow) * K + k0 + schunk * 8, &As[(w * 2 + 1) * 512]);
        gld16(Bt + (size_t)(tileN + w * 32 + srow) * K + k0 + schunk * 8, &Bs[(w * 2) * 512]);
        gld16(Bt + (size_t)(tileN + w * 32 + 16 + srow) * K + k0 + schunk * 8, &Bs[(w * 2 + 1) * 512]);
        __syncthreads();

        bf16x8 af[4], bf[4];
        for (int im = 0; im < 4; ++im)
            af[im] = *(const bf16x8*)&As[(waveM + im * 16 + mrow) * 32 + g8];
        for (int in = 0; in < 4; ++in)
            bf[in] = *(const bf16x8*)&Bs[(waveN + in * 16 + mrow) * 32 + g8];
        for (int im = 0; im < 4; ++im)
            for (int in = 0; in < 4; ++in)
                acc[im][in] = mfma16(af[im], bf[in], acc[im][in]);
        __syncthreads();
    }

    // epilogue. C/D layout: row=(l>>4)*4+r, col=l&15  [m89/m91]
    const int rbase = (l >> 4) * 4;
    for (int im = 0; im < 4; ++im) {
        for (int in = 0; in < 4; ++in) {
            const int gm0 = tileM + waveM + im * 16 + rbase;
            const int gn = tileN + waveN + in * 16 + (l & 15);
            const float bv_ = bias[gn];
            if (MODE == 1) {
                float* out = (float*)Cout;
                for (int r = 0; r < 4; ++r)
                    out[(size_t)(gm0 + r) * ldc + gn] = acc[im][in][r] + bv_;
            } else if (tileN < 2048) {
                // fold softmax scale * log2e into Q so attn softmax needs no scaling
                const float qs = (tileN < 1024) ? 0.125f * 1.4426950408889634f : 1.0f;
                u16* out = (u16*)Cout;  // qk, row-major (token, 2048)
                for (int r = 0; r < 4; ++r)
                    out[(size_t)(gm0 + r) * 2048 + gn] = f2b((acc[im][in][r] + bv_) * qs);
            } else {
                u16* out = (u16*)Cout2;  // V^T scatter (B,H,Dh,S)
                const int b = gm0 >> 11, s0 = gm0 & 2047;
                const int gn2 = gn - 2048;
                const int h = gn2 >> 6, dh = gn2 & 63;
                ushort4 u;
                u.x = f2b(acc[im][in][0] + bv_);
                u.y = f2b(acc[im][in][1] + bv_);
                u.z = f2b(acc[im][in][2] + bv_);
                u.w = f2b(acc[im][in][3] + bv_);
                *(ushort4*)&out[((size_t)((b * 16 + h) * 64 + dh)) * 2048 + s0] = u;
            }
        }
    }
}

// ---------------------------------------------------------------- flash attention
// R4 structure: 256 thr = 4 waves, 128 queries/block (wave w owns [q0+w*32, +32)
// as two 16-col groups; K/V LDS fragments shared across both groups). ONE q-tile
// per block; grid (bh=64, qt=16) = 1024 blocks -> 4 blocks/CU resident (LDS 36 KB),
// doubling cross-block overlap of the barrier convoys vs R4's 512-block pairing.
// Big tiles first (qt = 15-y); bh on x keeps bh%8 XCD striping for K/V L2 locality.
// Q arrives pre-scaled by 0.125*log2e (folded into gemm<0> epilogue).
__global__ __launch_bounds__(256, 2) void attn_kernel(const u16* __restrict__ qk,
                                                      const u16* __restrict__ vt,
                                                      u16* __restrict__ attn) {
    const int bh = blockIdx.x;
    const int qt = 15 - (int)blockIdx.y;  // big q-tiles launch first
    const int b = bh >> 4, h = bh & 15;
    const int q0 = qt * 128;
    const int tid = threadIdx.x, l = tid & 63, w = tid >> 6;
    const int q = l & 15;   // query column within group
    const int g = l >> 4;   // k-group
    const int g8 = g * 8;

    __shared__ u16 Ks[64 * 72];   // [key][dh]
    __shared__ u16 Vs[64 * 72];   // [dh][key]
    __shared__ u16 Ps[128 * 72];  // Q staging, then per-wave P slabs [query][key]

    const int srow = tid >> 3, sch = tid & 7;  // staging: 32 rows x 8 chunks, x2 passes
    const u16* kgb = qk + (size_t)(b * 2048 + srow) * 2048 + 1024 + h * 64 + sch * 8;
    const u16* vgb = vt + (size_t)(bh * 64 + srow) * 2048 + sch * 8;

    // stage Q tile (128 rows x 64 cols): 4 passes of 256 thr x 16B
    for (int i = 0; i < 4; ++i) {
        const int idx = i * 256 + tid;
        const int row = idx >> 3, ch = idx & 7;
        *(uint4*)&Ps[row * 72 + ch * 8] =
            *(const uint4*)&qk[(size_t)(b * 2048 + q0 + row) * 2048 + h * 64 + ch * 8];
    }
    __syncthreads();
    bf16x8 qb[2][2];  // [col-group][kh]
    for (int c = 0; c < 2; ++c) {
        qb[c][0] = *(const bf16x8*)&Ps[(w * 32 + c * 16 + q) * 72 + g8];
        qb[c][1] = *(const bf16x8*)&Ps[(w * 32 + c * 16 + q) * 72 + 32 + g8];
    }

    float m2[2] = {-1e30f, -1e30f}, li[2] = {0.f, 0.f};
    f32x4 o[2][4] = {};
    const int tmax = 2 * qt + 1;                  // block's last key tile
    const int tdiag = (q0 + w * 32 + 31) >> 6;    // this wave's diagonal tile

    uint4 kreg[2], vreg[2];  // coalesced prefetch of tile 0 (32 rows/pass x 2)
    for (int j = 0; j < 2; ++j) {
        kreg[j] = *(const uint4*)(kgb + (size_t)(j * 32) * 2048);
        vreg[j] = *(const uint4*)(vgb + (size_t)(j * 32) * 2048);
    }

    for (int t = 0; t <= tmax; ++t) {
        __syncthreads();  // prev tile compute done
        for (int j = 0; j < 2; ++j) {
            *(uint4*)&Ks[(srow + j * 32) * 72 + sch * 8] = kreg[j];
            *(uint4*)&Vs[(srow + j * 32) * 72 + sch * 8] = vreg[j];
        }
        __syncthreads();  // staging visible
        if (t < tmax) {   // coalesced prefetch of tile t+1 (overlaps compute)
            for (int j = 0; j < 2; ++j) {
                // K rows are tokens: advance (t+1)*64 rows
                kreg[j] = *(const uint4*)(kgb + (size_t)((t + 1) * 64 + j * 32) * 2048);
                // V^T rows are dh: key tile advances along COLUMNS (+64 elems/tile)
                vreg[j] = *(const uint4*)(vgb + (size_t)(j * 32) * 2048 + (t + 1) * 64);
            }
        }
        if (t > tdiag) continue;  // whole wave masked for this tile
        const int kv0 = t * 64;

        // S^T = K @ Q^T : K A-frags shared across both query groups
        f32x4 st[2][4] = {};
        for (int kh = 0; kh < 2; ++kh)
            for (int cb = 0; cb < 4; ++cb) {
                bf16x8 ka = *(const bf16x8*)&Ks[(cb * 16 + q) * 72 + kh * 32 + g8];
                st[0][cb] = mfma16(ka, qb[0][kh], st[0][cb]);
                st[1][cb] = mfma16(ka, qb[1][kh], st[1][cb]);
            }
        for (int c = 0; c < 2; ++c) {
            if (t == tdiag) {  // only the wave's diagonal tile has masked keys
                const int qg = q0 + w * 32 + c * 16 + q;
                for (int cb = 0; cb < 4; ++cb)
                    for (int r = 0; r < 4; ++r) {
                        const int key = kv0 + cb * 16 + g * 4 + r;
                        if (key > qg) st[c][cb][r] = -1e30f;
                    }
            }
            float mx = st[c][0][0];
            for (int cb = 0; cb < 4; ++cb)
                for (int r = 0; r < 4; ++r) mx = fmaxf(mx, st[c][cb][r]);
            mx = fmaxf(mx, __shfl_xor(mx, 16));
            mx = fmaxf(mx, __shfl_xor(mx, 32));
            const float mnew = fmaxf(m2[c], mx);
            const float alpha = __builtin_amdgcn_exp2f(m2[c] - mnew);
            m2[c] = mnew;
            float ps = 0.f;
            for (int cb = 0; cb < 4; ++cb)
                for (int r = 0; r < 4; ++r) {
                    const float p = __builtin_amdgcn_exp2f(st[c][cb][r] - mnew);
                    st[c][cb][r] = p;
                    ps += p;
                }
            ps += __shfl_xor(ps, 16);
            ps += __shfl_xor(ps, 32);
            li[c] = li[c] * alpha + ps;
            for (int cb = 0; cb < 4; ++cb) o[c][cb] *= alpha;
            // P^T C-regs -> Ps[query][key] (r=0..3 consecutive keys -> b64)
            for (int cb = 0; cb < 4; ++cb) {
                ushort4 u;
                u.x = f2b(st[c][cb][0]); u.y = f2b(st[c][cb][1]);
                u.z = f2b(st[c][cb][2]); u.w = f2b(st[c][cb][3]);
                *(ushort4*)&Ps[(w * 32 + c * 16 + q) * 72 + cb * 16 + g * 4] = u;
            }
        }
        __builtin_amdgcn_s_waitcnt(0xC07F);  // lgkmcnt(0); DS in-order per wave
        // O^T += V^T @ P^T : V A-frags shared across both query groups
        for (int kh = 0; kh < 2; ++kh) {
            bf16x8 pb0 = *(const bf16x8*)&Ps[(w * 32 + q) * 72 + kh * 32 + g8];
            bf16x8 pb1 = *(const bf16x8*)&Ps[(w * 32 + 16 + q) * 72 + kh * 32 + g8];
            for (int cb = 0; cb < 4; ++cb) {
                bf16x8 va = *(const bf16x8*)&Vs[(cb * 16 + q) * 72 + kh * 32 + g8];
                o[0][cb] = mfma16(va, pb0, o[0][cb]);
                o[1][cb] = mfma16(va, pb1, o[1][cb]);
            }
        }
    }

    // epilogue: attn[token][h*64+dh], dh = cb*16+g*4+r contiguous
    for (int c = 0; c < 2; ++c) {
        const float inv = 1.0f / li[c];
        const size_t tok = (size_t)(b * 2048 + q0 + w * 32 + c * 16 + q);
        for (int cb = 0; cb < 4; ++cb) {
            ushort4 u;
            u.x = f2b(o[c][cb][0] * inv); u.y = f2b(o[c][cb][1] * inv);
            u.z = f2b(o[c][cb][2] * inv); u.w = f2b(o[c][cb][3] * inv);
            *(ushort4*)&attn[tok * 1024 + h * 64 + cb * 16 + g * 4] = u;
        }
    }
}

// ---------------------------------------------------------------- launch
extern "C" void kernel_launch(void* const* d_in, const int* in_sizes, int n_in,
                              void* d_out, int out_size, void* d_ws, size_t ws_size,
                              hipStream_t stream) {
    const float* x  = (const float*)d_in[0];
    const float* Wq = (const float*)d_in[1];
    const float* bq = (const float*)d_in[2];
    const float* Wk = (const float*)d_in[3];
    const float* bk = (const float*)d_in[4];
    const float* Wv = (const float*)d_in[5];
    const float* bv = (const float*)d_in[6];
    const float* Wo = (const float*)d_in[7];
    const float* bo = (const float*)d_in[8];
    float* out = (float*)d_out;

    char* ws = (char*)d_ws;
    size_t off = 0;
    auto alloc = [&](size_t bytes) -> void* {
        void* p = ws + off;
        off += (bytes + 255) & ~(size_t)255;
        return p;
    };
    u16*   xb    = (u16*)alloc(8192ull * 1024 * 2);   // x bf16
    u16*   wqkvt = (u16*)alloc(3072ull * 1024 * 2);   // [Wq|Wk|Wv]^T (N,K)
    u16*   wot   = (u16*)alloc(1024ull * 1024 * 2);   // Wo^T
    float* bqkv  = (float*)alloc(3072ull * 4);
    u16*   qk    = (u16*)alloc(8192ull * 2048 * 2);   // [q|k] (token, 2048)
    u16*   vt    = (u16*)alloc(8192ull * 1024 * 2);   // V^T (B,H,Dh,S)
    u16*   attn  = (u16*)alloc(8192ull * 1024 * 2);   // attention out (token, D)

    convert_x<<<8192, 256, 0, stream>>>(x, xb, 8192 * 1024 / 4);
    transpose_w<<<dim3(32, 32, 4), dim3(32, 8), 0, stream>>>(Wq, Wk, Wv, Wo, wqkvt, wot);
    pack_bqkv<<<12, 256, 0, stream>>>(bq, bk, bv, bqkv);
    gemm_bt<0><<<dim3(64, 24), 256, 0, stream>>>(xb, wqkvt, bqkv, qk, vt, 8192, 3072, 1024, 0);
    attn_kernel<<<dim3(64, 16), 256, 0, stream>>>(qk, vt, attn);
    gemm_bt<1><<<dim3(64, 8), 256, 0, stream>>>(attn, wot, bo, out, nullptr, 8192, 1024, 1024, 1024);
}